// Round 1
// baseline (2688.286 us; speedup 1.0000x reference)
//
#include <hip/hip_runtime.h>

// GRU scan, persistent kernel. B=512, S=1024, I=64, H=256, G=3H=768, NC=10.
// 32 workgroups x 512 threads (8 waves). Block bg owns batch rows [16*bg, 16*bg+16).
// Wave w owns h-cols [32w, 32w+32) -> gate col-tiles {2w,2w+1, 16+2w,17+2w, 32+2w,33+2w}.
// Wh resident in VGPRs as MFMA B-frags (192 VGPR/lane); Wx in LDS (frag order);
// h ping-pong in LDS in A-frag order (bf16). One __syncthreads per timestep.

typedef short v8s __attribute__((ext_vector_type(8)));   // 8 bf16 (4 VGPRs)
typedef float f32x4 __attribute__((ext_vector_type(4))); // MFMA acc

#define LDS_WX   0        // 96 frags * 64 lanes * 16B = 98304
#define LDS_H    98304    // 2 * 8192 (8 ks * 64 lanes * 16B each)
#define LDS_X    114688   // 2 * 2048 (2 ks * 64 lanes * 16B each)
#define LDS_SIZE 118784

__device__ __forceinline__ unsigned short f2b(float f) {
    unsigned int u = __float_as_uint(f);
    u += 0x7FFFu + ((u >> 16) & 1u);       // RNE
    return (unsigned short)(u >> 16);
}
__device__ __forceinline__ float b2f(unsigned short h) {
    return __uint_as_float(((unsigned int)h) << 16);
}
__device__ __forceinline__ v8s cvt8(f32x4 a, f32x4 b) {
    v8s r;
#pragma unroll
    for (int j = 0; j < 4; ++j) { r[j] = (short)f2b(a[j]); r[4 + j] = (short)f2b(b[j]); }
    return r;
}
__device__ __forceinline__ float rcpf(float v) {
#if __has_builtin(__builtin_amdgcn_rcpf)
    return __builtin_amdgcn_rcpf(v);
#else
    return 1.0f / v;
#endif
}
__device__ __forceinline__ float sigm(float v) {
    float e = __expf(-fmaxf(v, -30.0f));
    return rcpf(1.0f + e);
}
__device__ __forceinline__ float tanh_(float v) {
    float vc = fmaxf(fminf(v, 30.0f), -30.0f);
    float e = __expf(-2.0f * vc);
    return (1.0f - e) * rcpf(1.0f + e);
}
__device__ __forceinline__ f32x4 MF(v8s a, v8s b, f32x4 c) {
    return __builtin_amdgcn_mfma_f32_16x16x32_bf16(a, b, c, 0, 0, 0);
}

// A-frag order index for element (row, k): u16 units
__device__ __forceinline__ int fidx(int row, int k) {
    return ((k >> 5) << 9) + ((((k >> 3) & 3) << 4) + row) * 8 + (k & 7);
}

// stage x[b0..b0+15, t, 0:64] (fp32) -> bf16 A-frag order into xdst (2048 B)
__device__ __forceinline__ void stage_x(const float* __restrict__ x, char* xdst, int b0, int t, int tid) {
    int r = tid >> 5;
    int c = (tid & 31) << 1;
    const float* src = x + (((size_t)(b0 + r)) << 16) + (t << 6) + c;
    float v0 = src[0], v1 = src[1];
    unsigned int pk = (unsigned int)f2b(v0) | ((unsigned int)f2b(v1) << 16);
    int idx = fidx(r, c);                       // even -> u32 aligned
    *(unsigned int*)(xdst + idx * 2) = pk;
}

extern "C" __global__ void __launch_bounds__(512, 2)
gru_scan(const float* __restrict__ x, const float* __restrict__ Wx,
         const float* __restrict__ Wh, const float* __restrict__ bias,
         const float* __restrict__ fcw, const float* __restrict__ fcb,
         float* __restrict__ out)
{
    extern __shared__ char lds[];
    char* wxl = lds + LDS_WX;
    char* hl  = lds + LDS_H;
    char* xl  = lds + LDS_X;

    const int tid = threadIdx.x;
    const int w = tid >> 6, l = tid & 63;
    const int cl = l & 15, kg = l >> 4;
    const int b0 = blockIdx.x << 4;

    int tiles[6] = {2 * w, 2 * w + 1, 16 + 2 * w, 17 + 2 * w, 32 + 2 * w, 33 + 2 * w};

    // ---- resident Wh B-fragments: [6 col-tiles][8 k-steps], 192 VGPRs ----
    v8s whB[6][8];
#pragma unroll
    for (int tt = 0; tt < 6; ++tt) {
        const float* src = Wh + (size_t)(tiles[tt] * 16 + cl) * 256 + kg * 8;
#pragma unroll
        for (int ks = 0; ks < 8; ++ks) {
            f32x4 a = *(const f32x4*)(src + ks * 32);
            f32x4 b = *(const f32x4*)(src + ks * 32 + 4);
            whB[tt][ks] = cvt8(a, b);
        }
    }

    // ---- bias registers (loop-invariant, lane-mapped) ----
    float brv[2], bzv[2], bhv[2];
#pragma unroll
    for (int p = 0; p < 2; ++p) {
        int ch = (w << 5) + (p << 4) + cl;
        brv[p] = bias[ch];
        bzv[p] = bias[256 + ch];
        bhv[p] = bias[512 + ch];
    }

    // ---- Wx -> LDS in B-frag order ----
    v8s* wxf = (v8s*)wxl;
    for (int fid = w; fid < 96; fid += 8) {
        int ct = fid >> 1, k2 = fid & 1;
        const float* src = Wx + (size_t)(ct * 16 + cl) * 64 + k2 * 32 + kg * 8;
        f32x4 a = *(const f32x4*)src;
        f32x4 b = *(const f32x4*)(src + 4);
        wxf[fid * 64 + l] = cvt8(a, b);
    }

    // ---- h0 = 0 (buffer 0), stage x_0 (parity 0) ----
    for (int i = tid; i < 2048; i += 512) ((unsigned int*)hl)[i] = 0u;
    stage_x(x, xl, b0, 0, tid);

    // ================= scan =================
    for (int t = 0; t < 1024; ++t) {
        __syncthreads();
        const int cur = t & 1;
        const v8s* hb = (const v8s*)(hl + cur * 8192);
        const v8s* xb = (const v8s*)(xl + cur * 2048);

        // acc: 0,1=r  2,3=z  4,5=h_h(n)  6,7=i_h(n)
        f32x4 acc[8];
#pragma unroll
        for (int i = 0; i < 8; ++i) acc[i] = f32x4{0.0f, 0.0f, 0.0f, 0.0f};

#pragma unroll
        for (int ks = 0; ks < 8; ++ks) {
            v8s a = hb[(ks << 6) + l];
#pragma unroll
            for (int tt = 0; tt < 6; ++tt)
                acc[tt] = MF(a, whB[tt][ks], acc[tt]);
        }
#pragma unroll
        for (int k2 = 0; k2 < 2; ++k2) {
            v8s ax = xb[(k2 << 6) + l];
#pragma unroll
            for (int tt = 0; tt < 4; ++tt)
                acc[tt] = MF(ax, wxf[(tiles[tt] * 2 + k2) * 64 + l], acc[tt]);
            acc[6] = MF(ax, wxf[(tiles[4] * 2 + k2) * 64 + l], acc[6]);
            acc[7] = MF(ax, wxf[(tiles[5] * 2 + k2) * 64 + l], acc[7]);
        }

        // ---- elementwise GRU update; write h_new into other buffer ----
        const unsigned short* hc16 = (const unsigned short*)hb;
        unsigned short* hn16 = (unsigned short*)(hl + (cur ^ 1) * 8192);
#pragma unroll
        for (int p = 0; p < 2; ++p) {
            int ch = (w << 5) + (p << 4) + cl;
            int chbase = ((ch >> 5) << 9) + (((ch >> 3) & 3) << 7) + (ch & 7);
#pragma unroll
            for (int i = 0; i < 4; ++i) {
                int row = (kg << 2) + i;
                int idx = chbase + (row << 3);
                float rg = sigm(acc[p][i] + brv[p]);
                float zg = sigm(acc[2 + p][i] + bzv[p]);
                float ng = tanh_(acc[6 + p][i] + bhv[p] + rg * acc[4 + p][i]);
                float hold = b2f(hc16[idx]);
                float hy = ng + zg * (hold - ng);
                hn16[idx] = f2b(hy);
            }
        }

        if (t + 1 < 1024) stage_x(x, xl + (cur ^ 1) * 2048, b0, t + 1, tid);
    }

    __syncthreads();
    // ---- logits: hT (buffer 0) @ fc_w.T + fc_b ----
    const unsigned short* hf = (const unsigned short*)hl;
    if (tid < 160) {
        int row = tid / 10, cls = tid - row * 10;
        float s = fcb[cls];
        const float* wrow = fcw + cls * 256;
        for (int k = 0; k < 256; ++k)
            s += b2f(hf[fidx(row, k)]) * wrow[k];
        out[(b0 + row) * 10 + cls] = s;
    }
}

extern "C" void kernel_launch(void* const* d_in, const int* in_sizes, int n_in,
                              void* d_out, int out_size, void* d_ws, size_t ws_size,
                              hipStream_t stream) {
    const float* x    = (const float*)d_in[0];
    const float* Wx   = (const float*)d_in[1];
    const float* Wh   = (const float*)d_in[2];
    const float* bias = (const float*)d_in[3];
    const float* fcw  = (const float*)d_in[4];
    const float* fcb  = (const float*)d_in[5];

    (void)hipFuncSetAttribute((const void*)gru_scan,
                              hipFuncAttributeMaxDynamicSharedMemorySize, LDS_SIZE);
    gru_scan<<<dim3(32), dim3(512), LDS_SIZE, stream>>>(x, Wx, Wh, bias, fcw, fcb,
                                                        (float*)d_out);
}